// Round 1
// baseline (905.014 us; speedup 1.0000x reference)
//
#include <hip/hip_runtime.h>

#define BS 32
#define Nn 2048
#define Ww 128
#define Rr 8
#define EPSF 1e-8f

// workspace layout (float offsets)
#define OFF_ALLOC   0
#define OFF_WW      (OFF_ALLOC + BS*Nn)
#define OFF_MEMNEW  (OFF_WW + BS*Nn)
#define OFF_MEMNORM (OFF_MEMNEW + Nn*Ww)
#define OFF_CR      (OFF_MEMNORM + Nn)
#define OFF_BW      (OFF_CR + BS*Nn*Rr)
#define OFF_FW      (OFF_BW + BS*Nn*Rr)

// ---------------------------------------------------------------- K1: alloc
// stable (value,index) bitonic sort + exclusive cumprod + reference's gather
__global__ void k_alloc(const float* __restrict__ usage, float* __restrict__ alloc_out)
{
    __shared__ float sv[Nn];
    __shared__ int   si[Nn];
    __shared__ float sp[256];
    int b = blockIdx.x, tx = threadIdx.x;
    for (int i = tx; i < Nn; i += 256) { sv[i] = usage[b*Nn + i]; si[i] = i; }
    __syncthreads();
    for (int k = 2; k <= Nn; k <<= 1) {
        for (int j = k >> 1; j > 0; j >>= 1) {
            for (int i = tx; i < Nn; i += 256) {
                int ixj = i ^ j;
                if (ixj > i) {
                    bool up = ((i & k) == 0);
                    float va = sv[i], vb = sv[ixj];
                    int   ia = si[i], ib = si[ixj];
                    bool gt = (va > vb) || (va == vb && ia > ib);
                    if (up ? gt : !gt) {
                        sv[i] = vb; sv[ixj] = va;
                        si[i] = ib; si[ixj] = ia;
                    }
                }
            }
            __syncthreads();
        }
    }
    // two-level exclusive cumprod over sorted values
    float p = 1.f;
    #pragma unroll
    for (int e = 0; e < 8; ++e) p *= sv[tx*8 + e];
    sp[tx] = p;
    __syncthreads();
    if (tx == 0) {
        float run = 1.f;
        for (int s = 0; s < 256; ++s) { float t = sp[s]; sp[s] = run; run *= t; }
    }
    __syncthreads();
    {
        float run = sp[tx];
        #pragma unroll
        for (int e = 0; e < 8; ++e) {
            float v = sv[tx*8 + e];
            sv[tx*8 + e] = (1.f - v) * run;   // alloc_sorted by rank (own segment only)
            run *= v;
        }
    }
    __syncthreads();
    // reference: alloc[i] = alloc_sorted[ indices[i] ]  (a gather by the argsort array)
    for (int i = tx; i < Nn; i += 256) alloc_out[b*Nn + i] = sv[si[i]];
}

// ---------------------------------------------------------------- K2: cw -> ww
__global__ void k_ww(const float* __restrict__ mem, const float* __restrict__ wkey,
                     const float* __restrict__ wstr, const float* __restrict__ agate,
                     const float* __restrict__ wgate, const float* __restrict__ allocv,
                     float* __restrict__ ww_out)
{
    __shared__ float s_wk[Ww];
    __shared__ float s_sim[Nn];
    __shared__ float s_red[256];
    int b = blockIdx.x, tx = threadIdx.x;
    if (tx < Ww) s_wk[tx] = wkey[b*Ww + tx];
    __syncthreads();
    float wn2 = 0.f;
    #pragma unroll
    for (int w = 0; w < Ww; ++w) { float k = s_wk[w]; wn2 += k*k; }
    float wn = sqrtf(wn2);
    float st = wstr[b];
    for (int n = tx; n < Nn; n += 256) {
        const float* mrow = mem + n*Ww;
        float dot = 0.f, m2 = 0.f;
        for (int w = 0; w < Ww; w += 4) {
            float4 m4 = *(const float4*)(mrow + w);
            float4 k4 = *(const float4*)(&s_wk[w]);
            dot += m4.x*k4.x + m4.y*k4.y + m4.z*k4.z + m4.w*k4.w;
            m2  += m4.x*m4.x + m4.y*m4.y + m4.z*m4.z + m4.w*m4.w;
        }
        float denom = fmaxf(sqrtf(m2)*wn, EPSF);
        s_sim[n] = dot / denom * st;
    }
    __syncthreads();
    float lm = -3.402823466e38f;
    for (int n = tx; n < Nn; n += 256) lm = fmaxf(lm, s_sim[n]);
    s_red[tx] = lm; __syncthreads();
    for (int s = 128; s > 0; s >>= 1) { if (tx < s) s_red[tx] = fmaxf(s_red[tx], s_red[tx+s]); __syncthreads(); }
    float mx = s_red[0]; __syncthreads();
    float ls = 0.f;
    for (int n = tx; n < Nn; n += 256) ls += expf(s_sim[n] - mx);
    s_red[tx] = ls; __syncthreads();
    for (int s = 128; s > 0; s >>= 1) { if (tx < s) s_red[tx] += s_red[tx+s]; __syncthreads(); }
    float inv = 1.f / s_red[0];
    float ag = agate[b], wg = wgate[b];
    for (int n = tx; n < Nn; n += 256) {
        float cw = expf(s_sim[n] - mx) * inv;
        ww_out[b*Nn + n] = wg * (ag * allocv[b*Nn + n] + (1.f - ag) * cw);
    }
}

// ---------------------------------------------------------------- K3: memory_new + row norms
__global__ void k_memnew(const float* __restrict__ mem, const float* __restrict__ ww,
                         const float* __restrict__ erasev, const float* __restrict__ wvec,
                         float* __restrict__ memnew, float* __restrict__ memnorm)
{
    __shared__ float s_red[2][Ww];
    int tx = threadIdx.x;
    int h = tx >> 7, w = tx & 127;
    int n = blockIdx.x * 2 + h;
    float accE = 0.f, accA = 0.f;
    for (int b = 0; b < BS; ++b) {
        float wwv = ww[b*Nn + n];
        accE += wwv * erasev[b*Ww + w];
        accA += wwv * wvec[b*Ww + w];
    }
    const float inv = 1.f / (float)BS;
    float m = mem[n*Ww + w];
    float outv = m * (1.f - accE*inv) + accA*inv;
    memnew[n*Ww + w] = outv;
    s_red[h][w] = outv*outv;
    __syncthreads();
    for (int s = 64; s > 0; s >>= 1) { if (w < s) s_red[h][w] += s_red[h][w+s]; __syncthreads(); }
    if (w == 0) memnorm[n] = sqrtf(s_red[h][0]);
}

// ---------------------------------------------------------------- K4: content read weighting (softmax over n)
__global__ void k_cr(const float* __restrict__ memnew, const float* __restrict__ memnorm,
                     const float* __restrict__ rkeys, const float* __restrict__ rstr,
                     float* __restrict__ cr)
{
    __shared__ float s_key[Ww];
    __shared__ float s_sim[Nn];
    __shared__ float s_red[256];
    int b = blockIdx.x >> 3, r = blockIdx.x & 7;
    int tx = threadIdx.x;
    if (tx < Ww) s_key[tx] = rkeys[(b*Ww + tx)*Rr + r];
    __syncthreads();
    float kn2 = 0.f;
    #pragma unroll
    for (int w = 0; w < Ww; ++w) { float k = s_key[w]; kn2 += k*k; }
    float kn = sqrtf(kn2);
    float st = rstr[b*Rr + r];
    for (int n = tx; n < Nn; n += 256) {
        const float* mrow = memnew + n*Ww;
        float dot = 0.f;
        for (int w = 0; w < Ww; w += 4) {
            float4 m4 = *(const float4*)(mrow + w);
            float4 k4 = *(const float4*)(&s_key[w]);
            dot += m4.x*k4.x + m4.y*k4.y + m4.z*k4.z + m4.w*k4.w;
        }
        float denom = fmaxf(memnorm[n]*kn, EPSF);
        s_sim[n] = dot / denom * st;
    }
    __syncthreads();
    float lm = -3.402823466e38f;
    for (int n = tx; n < Nn; n += 256) lm = fmaxf(lm, s_sim[n]);
    s_red[tx] = lm; __syncthreads();
    for (int s = 128; s > 0; s >>= 1) { if (tx < s) s_red[tx] = fmaxf(s_red[tx], s_red[tx+s]); __syncthreads(); }
    float mx = s_red[0]; __syncthreads();
    float ls = 0.f;
    for (int n = tx; n < Nn; n += 256) ls += expf(s_sim[n] - mx);
    s_red[tx] = ls; __syncthreads();
    for (int s = 128; s > 0; s >>= 1) { if (tx < s) s_red[tx] += s_red[tx+s]; __syncthreads(); }
    float inv = 1.f / s_red[0];
    for (int n = tx; n < Nn; n += 256)
        cr[((size_t)b*Nn + n)*Rr + r] = expf(s_sim[n] - mx) * inv;
}

// ---------------------------------------------------------------- K5: fused L_new -> bw, fw (the 512MB pass)
#define TI 128
__global__ __launch_bounds__(256) void k_link(const float* __restrict__ L,
    const float* __restrict__ ww, const float* __restrict__ prec,
    const float* __restrict__ lrw, float* __restrict__ bw, float* __restrict__ fw)
{
    __shared__ float  s_wwi[TI];
    __shared__ float4 s_lri[TI][2];
    __shared__ float  s_bw[4][TI][Rr];     // per-wave partial planes (no atomics)
    int b    = blockIdx.x >> 4;            // 16 row-tiles per batch
    int tile = blockIdx.x & 15;
    int i0 = tile * TI;
    int tx = threadIdx.x;
    int wv = tx >> 6;
    for (int k = tx; k < TI; k += 256) s_wwi[k] = ww[b*Nn + i0 + k];
    for (int k = tx; k < TI*2; k += 256)
        s_lri[k>>1][k&1] = *(const float4*)(lrw + ((size_t)b*Nn + i0 + (k>>1))*Rr + (k&1)*4);
    for (int k = tx; k < 4*TI*Rr; k += 256) ((float*)s_bw)[k] = 0.f;
    __syncthreads();
    const float* Lb = L + (size_t)b*Nn*Nn;
    for (int jc = 0; jc < Nn; jc += 1024) {
        int j = jc + tx*4;                 // thread owns 4 consecutive columns
        float4 wwj = *(const float4*)(ww + b*Nn + j);
        float4 pj  = *(const float4*)(prec + b*Nn + j);
        float aj[4]  = {1.f-wwj.x, 1.f-wwj.y, 1.f-wwj.z, 1.f-wwj.w};
        float pjv[4] = {pj.x, pj.y, pj.z, pj.w};
        float lro[4][Rr];
        #pragma unroll
        for (int jj = 0; jj < 4; ++jj) {
            float4 a = *(const float4*)(lrw + ((size_t)b*Nn + j + jj)*Rr);
            float4 c = *(const float4*)(lrw + ((size_t)b*Nn + j + jj)*Rr + 4);
            lro[jj][0]=a.x; lro[jj][1]=a.y; lro[jj][2]=a.z; lro[jj][3]=a.w;
            lro[jj][4]=c.x; lro[jj][5]=c.y; lro[jj][6]=c.z; lro[jj][7]=c.w;
        }
        float fwo[4][Rr];
        #pragma unroll
        for (int jj = 0; jj < 4; ++jj)
            #pragma unroll
            for (int r = 0; r < Rr; ++r) fwo[jj][r] = 0.f;

        for (int i = 0; i < TI; ++i) {
            float wwi = s_wwi[i];
            float4 Lv = *(const float4*)(Lb + (size_t)(i0 + i)*Nn + j);
            float4 l0 = s_lri[i][0], l1 = s_lri[i][1];
            float lri[8] = {l0.x,l0.y,l0.z,l0.w,l1.x,l1.y,l1.z,l1.w};
            float lvv[4] = {Lv.x,Lv.y,Lv.z,Lv.w};
            float br[Rr] = {0,0,0,0,0,0,0,0};
            #pragma unroll
            for (int jj = 0; jj < 4; ++jj) {
                float l = (aj[jj] - wwi)*lvv[jj] + wwi*pjv[jj];
                #pragma unroll
                for (int r = 0; r < Rr; ++r) {
                    fwo[jj][r] += l * lri[r];     // column side: register-private
                    br[r]     += l * lro[jj][r];  // row side: needs wave reduce
                }
            }
            #pragma unroll
            for (int r = 0; r < Rr; ++r) {
                #pragma unroll
                for (int m = 1; m < 64; m <<= 1)
                    br[r] += __shfl_xor(br[r], m);
            }
            if ((tx & 63) == 0) {
                #pragma unroll
                for (int r = 0; r < Rr; ++r) s_bw[wv][i][r] += br[r];
            }
        }
        #pragma unroll
        for (int jj = 0; jj < 4; ++jj)
            #pragma unroll
            for (int r = 0; r < Rr; ++r)
                unsafeAtomicAdd(&fw[((size_t)b*Nn + j + jj)*Rr + r], fwo[jj][r]);
    }
    __syncthreads();
    for (int k = tx; k < TI*Rr; k += 256) {
        int i = k >> 3, r = k & 7;
        bw[((size_t)b*Nn + i0 + i)*Rr + r] =
            s_bw[0][i][r] + s_bw[1][i][r] + s_bw[2][i][r] + s_bw[3][i][r];
    }
}

// ---------------------------------------------------------------- K6: combine modes + read vectors
__global__ void k_read(const float* __restrict__ memnew, const float* __restrict__ bw,
                       const float* __restrict__ cr, const float* __restrict__ fw,
                       const float* __restrict__ rmodes, float* __restrict__ out)
{
    __shared__ float s_rw[256][Rr];
    __shared__ float s_rm[Rr*3];
    __shared__ float s_part[2][Ww][Rr];
    int b = blockIdx.x >> 3, slice = blockIdx.x & 7;
    int n0 = slice * 256;
    int tx = threadIdx.x;
    if (tx < Rr*3) s_rm[tx] = rmodes[b*Rr*3 + tx];
    __syncthreads();
    size_t base = ((size_t)b*Nn + n0)*Rr;
    for (int k = tx; k < 256*Rr; k += 256) {
        int nl = k >> 3, r = k & 7;
        s_rw[nl][r] = bw[base + k]*s_rm[r*3+0] + cr[base + k]*s_rm[r*3+1] + fw[base + k]*s_rm[r*3+2];
    }
    __syncthreads();
    int w = tx & 127, h = tx >> 7;
    float acc[Rr] = {0,0,0,0,0,0,0,0};
    for (int nl = h*128; nl < h*128+128; ++nl) {
        float mval = memnew[(n0 + nl)*Ww + w];
        #pragma unroll
        for (int r = 0; r < Rr; ++r) acc[r] += mval * s_rw[nl][r];
    }
    #pragma unroll
    for (int r = 0; r < Rr; ++r) s_part[h][w][r] = acc[r];
    __syncthreads();
    if (h == 0) {
        #pragma unroll
        for (int r = 0; r < Rr; ++r)
            unsafeAtomicAdd(&out[(b*Ww + w)*Rr + r], s_part[0][w][r] + s_part[1][w][r]);
    }
}

// ----------------------------------------------------------------
extern "C" void kernel_launch(void* const* d_in, const int* in_sizes, int n_in,
                              void* d_out, int out_size, void* d_ws, size_t ws_size,
                              hipStream_t stream) {
    const float* mem    = (const float*)d_in[0];
    const float* usage  = (const float*)d_in[1];
    const float* prec   = (const float*)d_in[2];
    const float* Lmat   = (const float*)d_in[3];
    const float* lrw    = (const float*)d_in[4];
    const float* rkeys  = (const float*)d_in[5];
    const float* rstr   = (const float*)d_in[6];
    const float* wkey   = (const float*)d_in[7];
    const float* wstr   = (const float*)d_in[8];
    const float* erasev = (const float*)d_in[9];
    const float* wvec   = (const float*)d_in[10];
    const float* agate  = (const float*)d_in[12];
    const float* wgate  = (const float*)d_in[13];
    const float* rmodes = (const float*)d_in[14];

    float* ws       = (float*)d_ws;
    float* alloc_   = ws + OFF_ALLOC;
    float* ww_      = ws + OFF_WW;
    float* memnew_  = ws + OFF_MEMNEW;
    float* memnorm_ = ws + OFF_MEMNORM;
    float* cr_      = ws + OFF_CR;
    float* bw_      = ws + OFF_BW;
    float* fw_      = ws + OFF_FW;
    float* outf     = (float*)d_out;

    hipMemsetAsync(fw_, 0, (size_t)BS*Nn*Rr*sizeof(float), stream);
    hipMemsetAsync(outf, 0, (size_t)out_size*sizeof(float), stream);

    k_alloc <<<BS,        256, 0, stream>>>(usage, alloc_);
    k_ww    <<<BS,        256, 0, stream>>>(mem, wkey, wstr, agate, wgate, alloc_, ww_);
    k_memnew<<<Nn/2,      256, 0, stream>>>(mem, ww_, erasev, wvec, memnew_, memnorm_);
    k_cr    <<<BS*Rr,     256, 0, stream>>>(memnew_, memnorm_, rkeys, rstr, cr_);
    k_link  <<<BS*(Nn/TI),256, 0, stream>>>(Lmat, ww_, prec, lrw, bw_, fw_);
    k_read  <<<BS*8,      256, 0, stream>>>(memnew_, bw_, cr_, fw_, rmodes, outf);
}

// Round 2
// 589.447 us; speedup vs baseline: 1.5354x; 1.5354x over previous
//
#include <hip/hip_runtime.h>

#define BS 32
#define Nn 2048
#define Ww 128
#define Rr 8
#define EPSF 1e-8f

// workspace layout (float offsets)
#define OFF_ALLOC   0
#define OFF_WW      (OFF_ALLOC + BS*Nn)
#define OFF_MEMNEW  (OFF_WW + BS*Nn)
#define OFF_MEMNORM (OFF_MEMNEW + Nn*Ww)
#define OFF_CR      (OFF_MEMNORM + Nn)
#define OFF_M2      (OFF_CR + BS*Nn*Rr)
#define OFF_O1      (OFF_M2 + BS*Nn*16)
#define OFF_C12     (OFF_O1 + BS*Nn*16)
#define OFF_PART    (OFF_C12 + BS*16)

__device__ __forceinline__ void gload_lds16(const void* g, void* l) {
    __builtin_amdgcn_global_load_lds((const __attribute__((address_space(1))) void*)g,
                                     (__attribute__((address_space(3))) void*)l, 16, 0, 0);
}

#define FMA16(ACC, LV, M0, M1, M2V, M3) \
    ACC[0]  += (LV)*(M0).x;  ACC[1]  += (LV)*(M0).y;  ACC[2]  += (LV)*(M0).z;  ACC[3]  += (LV)*(M0).w; \
    ACC[4]  += (LV)*(M1).x;  ACC[5]  += (LV)*(M1).y;  ACC[6]  += (LV)*(M1).z;  ACC[7]  += (LV)*(M1).w; \
    ACC[8]  += (LV)*(M2V).x; ACC[9]  += (LV)*(M2V).y; ACC[10] += (LV)*(M2V).z; ACC[11] += (LV)*(M2V).w; \
    ACC[12] += (LV)*(M3).x;  ACC[13] += (LV)*(M3).y;  ACC[14] += (LV)*(M3).z;  ACC[15] += (LV)*(M3).w;

// ---------------------------------------------------------------- K1: alloc
__global__ void k_alloc(const float* __restrict__ usage, float* __restrict__ alloc_out)
{
    __shared__ float sv[Nn];
    __shared__ int   si[Nn];
    __shared__ float sp[256];
    int b = blockIdx.x, tx = threadIdx.x;
    for (int i = tx; i < Nn; i += 256) { sv[i] = usage[b*Nn + i]; si[i] = i; }
    __syncthreads();
    for (int k = 2; k <= Nn; k <<= 1) {
        for (int j = k >> 1; j > 0; j >>= 1) {
            for (int i = tx; i < Nn; i += 256) {
                int ixj = i ^ j;
                if (ixj > i) {
                    bool up = ((i & k) == 0);
                    float va = sv[i], vb = sv[ixj];
                    int   ia = si[i], ib = si[ixj];
                    bool gt = (va > vb) || (va == vb && ia > ib);
                    if (up ? gt : !gt) {
                        sv[i] = vb; sv[ixj] = va;
                        si[i] = ib; si[ixj] = ia;
                    }
                }
            }
            __syncthreads();
        }
    }
    float p = 1.f;
    #pragma unroll
    for (int e = 0; e < 8; ++e) p *= sv[tx*8 + e];
    sp[tx] = p;
    __syncthreads();
    if (tx == 0) {
        float run = 1.f;
        for (int s = 0; s < 256; ++s) { float t = sp[s]; sp[s] = run; run *= t; }
    }
    __syncthreads();
    {
        float run = sp[tx];
        #pragma unroll
        for (int e = 0; e < 8; ++e) {
            float v = sv[tx*8 + e];
            sv[tx*8 + e] = (1.f - v) * run;
            run *= v;
        }
    }
    __syncthreads();
    for (int i = tx; i < Nn; i += 256) alloc_out[b*Nn + i] = sv[si[i]];
}

// ---------------------------------------------------------------- K2: cw -> ww
__global__ void k_ww(const float* __restrict__ mem, const float* __restrict__ wkey,
                     const float* __restrict__ wstr, const float* __restrict__ agate,
                     const float* __restrict__ wgate, const float* __restrict__ allocv,
                     float* __restrict__ ww_out)
{
    __shared__ float s_wk[Ww];
    __shared__ float s_sim[Nn];
    __shared__ float s_red[256];
    int b = blockIdx.x, tx = threadIdx.x;
    if (tx < Ww) s_wk[tx] = wkey[b*Ww + tx];
    __syncthreads();
    float wn2 = 0.f;
    #pragma unroll
    for (int w = 0; w < Ww; ++w) { float k = s_wk[w]; wn2 += k*k; }
    float wn = sqrtf(wn2);
    float st = wstr[b];
    for (int n = tx; n < Nn; n += 256) {
        const float* mrow = mem + n*Ww;
        float dot = 0.f, m2 = 0.f;
        for (int w = 0; w < Ww; w += 4) {
            float4 m4 = *(const float4*)(mrow + w);
            float4 k4 = *(const float4*)(&s_wk[w]);
            dot += m4.x*k4.x + m4.y*k4.y + m4.z*k4.z + m4.w*k4.w;
            m2  += m4.x*m4.x + m4.y*m4.y + m4.z*m4.z + m4.w*m4.w;
        }
        float denom = fmaxf(sqrtf(m2)*wn, EPSF);
        s_sim[n] = dot / denom * st;
    }
    __syncthreads();
    float lm = -3.402823466e38f;
    for (int n = tx; n < Nn; n += 256) lm = fmaxf(lm, s_sim[n]);
    s_red[tx] = lm; __syncthreads();
    for (int s = 128; s > 0; s >>= 1) { if (tx < s) s_red[tx] = fmaxf(s_red[tx], s_red[tx+s]); __syncthreads(); }
    float mx = s_red[0]; __syncthreads();
    float ls = 0.f;
    for (int n = tx; n < Nn; n += 256) ls += expf(s_sim[n] - mx);
    s_red[tx] = ls; __syncthreads();
    for (int s = 128; s > 0; s >>= 1) { if (tx < s) s_red[tx] += s_red[tx+s]; __syncthreads(); }
    float inv = 1.f / s_red[0];
    float ag = agate[b], wg = wgate[b];
    for (int n = tx; n < Nn; n += 256) {
        float cw = expf(s_sim[n] - mx) * inv;
        ww_out[b*Nn + n] = wg * (ag * allocv[b*Nn + n] + (1.f - ag) * cw);
    }
}

// ---------------------------------------------------------------- K3: memory_new + row norms
__global__ void k_memnew(const float* __restrict__ mem, const float* __restrict__ ww,
                         const float* __restrict__ erasev, const float* __restrict__ wvec,
                         float* __restrict__ memnew, float* __restrict__ memnorm)
{
    __shared__ float s_red[2][Ww];
    int tx = threadIdx.x;
    int h = tx >> 7, w = tx & 127;
    int n = blockIdx.x * 2 + h;
    float accE = 0.f, accA = 0.f;
    for (int b = 0; b < BS; ++b) {
        float wwv = ww[b*Nn + n];
        accE += wwv * erasev[b*Ww + w];
        accA += wwv * wvec[b*Ww + w];
    }
    const float inv = 1.f / (float)BS;
    float m = mem[n*Ww + w];
    float outv = m * (1.f - accE*inv) + accA*inv;
    memnew[n*Ww + w] = outv;
    s_red[h][w] = outv*outv;
    __syncthreads();
    for (int s = 64; s > 0; s >>= 1) { if (w < s) s_red[h][w] += s_red[h][w+s]; __syncthreads(); }
    if (w == 0) memnorm[n] = sqrtf(s_red[h][0]);
}

// ---------------------------------------------------------------- K4: content read weighting
__global__ void k_cr(const float* __restrict__ memnew, const float* __restrict__ memnorm,
                     const float* __restrict__ rkeys, const float* __restrict__ rstr,
                     float* __restrict__ cr)
{
    __shared__ float s_key[Ww];
    __shared__ float s_sim[Nn];
    __shared__ float s_red[256];
    int b = blockIdx.x >> 3, r = blockIdx.x & 7;
    int tx = threadIdx.x;
    if (tx < Ww) s_key[tx] = rkeys[(b*Ww + tx)*Rr + r];
    __syncthreads();
    float kn2 = 0.f;
    #pragma unroll
    for (int w = 0; w < Ww; ++w) { float k = s_key[w]; kn2 += k*k; }
    float kn = sqrtf(kn2);
    float st = rstr[b*Rr + r];
    for (int n = tx; n < Nn; n += 256) {
        const float* mrow = memnew + n*Ww;
        float dot = 0.f;
        for (int w = 0; w < Ww; w += 4) {
            float4 m4 = *(const float4*)(mrow + w);
            float4 k4 = *(const float4*)(&s_key[w]);
            dot += m4.x*k4.x + m4.y*k4.y + m4.z*k4.z + m4.w*k4.w;
        }
        float denom = fmaxf(memnorm[n]*kn, EPSF);
        s_sim[n] = dot / denom * st;
    }
    __syncthreads();
    float lm = -3.402823466e38f;
    for (int n = tx; n < Nn; n += 256) lm = fmaxf(lm, s_sim[n]);
    s_red[tx] = lm; __syncthreads();
    for (int s = 128; s > 0; s >>= 1) { if (tx < s) s_red[tx] = fmaxf(s_red[tx], s_red[tx+s]); __syncthreads(); }
    float mx = s_red[0]; __syncthreads();
    float ls = 0.f;
    for (int n = tx; n < Nn; n += 256) ls += expf(s_sim[n] - mx);
    s_red[tx] = ls; __syncthreads();
    for (int s = 128; s > 0; s >>= 1) { if (tx < s) s_red[tx] += s_red[tx+s]; __syncthreads(); }
    float inv = 1.f / s_red[0];
    for (int n = tx; n < Nn; n += 256)
        cr[((size_t)b*Nn + n)*Rr + r] = expf(s_sim[n] - mx) * inv;
}

// ---------------------------------------------------------------- K5a: prep M2 = [lr | ww*lr], c1, c2
__global__ void k_prep(const float* __restrict__ lrw, const float* __restrict__ ww,
                       const float* __restrict__ prec, float* __restrict__ M2,
                       float* __restrict__ c12)
{
    int b = blockIdx.x, tx = threadIdx.x;
    float c1p[8] = {0,0,0,0,0,0,0,0};
    float c2p[8] = {0,0,0,0,0,0,0,0};
    for (int j = tx; j < Nn; j += 256) {
        size_t jb = (size_t)b*Nn + j;
        float4 a  = *(const float4*)(lrw + jb*Rr);
        float4 b4 = *(const float4*)(lrw + jb*Rr + 4);
        float w = ww[jb], pv = prec[jb];
        float* dst = M2 + jb*16;
        ((float4*)dst)[0] = a;
        ((float4*)dst)[1] = b4;
        ((float4*)dst)[2] = make_float4(a.x*w,  a.y*w,  a.z*w,  a.w*w);
        ((float4*)dst)[3] = make_float4(b4.x*w, b4.y*w, b4.z*w, b4.w*w);
        c1p[0] += pv*a.x;  c1p[1] += pv*a.y;  c1p[2] += pv*a.z;  c1p[3] += pv*a.w;
        c1p[4] += pv*b4.x; c1p[5] += pv*b4.y; c1p[6] += pv*b4.z; c1p[7] += pv*b4.w;
        c2p[0] += w*a.x;   c2p[1] += w*a.y;   c2p[2] += w*a.z;   c2p[3] += w*a.w;
        c2p[4] += w*b4.x;  c2p[5] += w*b4.y;  c2p[6] += w*b4.z;  c2p[7] += w*b4.w;
    }
    __shared__ float sred[4][16];
    #pragma unroll
    for (int r = 0; r < 8; ++r) {
        float v1 = c1p[r], v2 = c2p[r];
        #pragma unroll
        for (int m = 1; m < 64; m <<= 1) { v1 += __shfl_xor(v1, m); v2 += __shfl_xor(v2, m); }
        c1p[r] = v1; c2p[r] = v2;
    }
    int wv = tx >> 6;
    if ((tx & 63) == 0) {
        #pragma unroll
        for (int r = 0; r < 8; ++r) { sred[wv][r] = c1p[r]; sred[wv][8+r] = c2p[r]; }
    }
    __syncthreads();
    if (tx < 16)
        c12[b*16 + tx] = sred[0][tx] + sred[1][tx] + sred[2][tx] + sred[3][tx];
}

// ---------------------------------------------------------------- K5: O1 = L@M2, partials of O2 = L^T@M2
// LDS tile swizzle: physical float4-slot p of row i holds logical quad (p ^ (i&15)).
template<int TI, int NT>
__global__ __launch_bounds__(256) void k_link(const float* __restrict__ L,
    const float* __restrict__ M2g, float* __restrict__ O1g, float* __restrict__ partg)
{
    constexpr int KTILE = TI / 16;     // gload_lds per thread for tile (8 or 16)
    constexpr int NIQ   = TI / 4;      // threads along rows in phase A (32 or 64)
    constexpr int NH    = 256 / NIQ;   // col-groups in phase A (8 or 4)
    constexpr int JJ4   = 16 / NH;     // f4-quads per col-group (2 or 4)
    constexpr int RB    = TI / 16;     // rows per thread in phase B (8 or 16)

    __shared__ float4 sTile[TI*16];
    __shared__ float4 sM2c[64*4];
    __shared__ float4 sM2r[TI*4];
    __shared__ float4 sComb[4*16*16];

    const int b    = blockIdx.x / NT;
    const int tile = blockIdx.x % NT;
    const int i0   = tile * TI;
    const int tx   = threadIdx.x;
    const int wv   = tx >> 6;

    const float* Lb  = L + (size_t)b*Nn*Nn;
    const float* M2b = M2g + (size_t)b*Nn*16;

    const int iq = tx & (NIQ-1);
    const int h  = tx / NIQ;
    const int jq = tx & 15;
    const int q  = tx >> 4;

    // stage M2row once (plain vector loads; broadcast-read later, no swizzle needed)
    for (int k = tx; k < TI*4; k += 256)
        sM2r[k] = *(const float4*)(M2b + (size_t)(i0 + (k>>2))*16 + (k&3)*4);

    auto stage = [&](int jc) {
        #pragma unroll
        for (int k = 0; k < KTILE; ++k) {
            int s = k*256 + tx;
            int i = s >> 4, j4s = s & 15;
            const float* src = Lb + (size_t)(i0 + i)*Nn + jc + 4*(j4s ^ (i & 15));
            gload_lds16(src, sTile + (k*256 + (wv<<6)));
        }
        {
            const float* src = M2b + (size_t)(jc + (tx>>2))*16 + (tx&3)*4;
            gload_lds16(src, sM2c + (wv<<6));
        }
    };

    float P[4][16];
    #pragma unroll
    for (int k = 0; k < 4; ++k)
        #pragma unroll
        for (int c = 0; c < 16; ++c) P[k][c] = 0.f;

    stage(0);
    __syncthreads();

    for (int t = 0; t < Nn/64; ++t) {
        const int jc = t*64;

        // ---- phase A: row-side, P[i][c] += L[i,j]*M2[j][c]
        #pragma unroll
        for (int jo = 0; jo < JJ4; ++jo) {
            const int jj4 = h*JJ4 + jo;
            float4 Lv[4];
            #pragma unroll
            for (int k = 0; k < 4; ++k) {
                int i = iq*4 + k;
                Lv[k] = sTile[i*16 + (jj4 ^ (i & 15))];
            }
            #pragma unroll
            for (int jj = 0; jj < 4; ++jj) {
                const int j = jj4*4 + jj;
                float4 m0 = sM2c[j*4+0], m1 = sM2c[j*4+1], m2v = sM2c[j*4+2], m3 = sM2c[j*4+3];
                #pragma unroll
                for (int k = 0; k < 4; ++k) {
                    const float lv = (jj==0)?Lv[k].x:(jj==1)?Lv[k].y:(jj==2)?Lv[k].z:Lv[k].w;
                    FMA16(P[k], lv, m0, m1, m2v, m3)
                }
            }
        }

        // ---- phase B: col-side, Pt[col][c] += L[i,j]*M2[i][c]
        float Pt[4][16];
        #pragma unroll
        for (int cc = 0; cc < 4; ++cc)
            #pragma unroll
            for (int c = 0; c < 16; ++c) Pt[cc][c] = 0.f;
        #pragma unroll
        for (int ii = 0; ii < RB; ++ii) {
            const int i = q*RB + ii;
            float4 Lv = sTile[i*16 + (jq ^ (i & 15))];
            float4 m0 = sM2r[i*4+0], m1 = sM2r[i*4+1], m2v = sM2r[i*4+2], m3 = sM2r[i*4+3];
            #pragma unroll
            for (int cc = 0; cc < 4; ++cc) {
                const float lv = (cc==0)?Lv.x:(cc==1)?Lv.y:(cc==2)?Lv.z:Lv.w;
                FMA16(Pt[cc], lv, m0, m1, m2v, m3)
            }
        }

        // in-wave 4-way combine (lanes q&3 share jq), then sComb (swizzled: f4 f at f^jq)
        #pragma unroll
        for (int cc = 0; cc < 4; ++cc)
            #pragma unroll
            for (int c = 0; c < 16; ++c) {
                float v = Pt[cc][c];
                v += __shfl_xor(v, 16);
                v += __shfl_xor(v, 32);
                Pt[cc][c] = v;
            }
        if ((tx & 63) < 16) {
            #pragma unroll
            for (int cc = 0; cc < 4; ++cc)
                #pragma unroll
                for (int c4 = 0; c4 < 4; ++c4) {
                    int f = cc*4 + c4;
                    sComb[(wv*16 + jq)*16 + (f ^ jq)] =
                        make_float4(Pt[cc][c4*4], Pt[cc][c4*4+1], Pt[cc][c4*4+2], Pt[cc][c4*4+3]);
                }
        }
        __syncthreads();            // tile reads done; sComb visible

        if (t+1 < Nn/64) stage(jc + 64);   // overwrite tile + m2c for next chunk

        {   // 4-wave sum of sComb, coalesced partial store (4 KB)
            int jqq = tx >> 4, inner = tx & 15;
            int slot = jqq*16 + (inner ^ jqq);
            float4 a0 = sComb[0*256 + slot];
            float4 a1 = sComb[1*256 + slot];
            float4 a2 = sComb[2*256 + slot];
            float4 a3 = sComb[3*256 + slot];
            float4 s;
            s.x = a0.x+a1.x+a2.x+a3.x; s.y = a0.y+a1.y+a2.y+a3.y;
            s.z = a0.z+a1.z+a2.z+a3.z; s.w = a0.w+a1.w+a2.w+a3.w;
            float* pdst = partg + ((size_t)(tile*BS + b)*Nn + jc)*16;
            ((float4*)pdst)[tx] = s;
        }
        __syncthreads();            // drains vmcnt(0): stage complete
    }

    // ---- O1 flush: combine NH col-group partials per row via LDS (reuse sComb)
    float4* sO1 = sComb;
    for (int hh = 0; hh < NH; ++hh) {
        if (h == hh) {
            #pragma unroll
            for (int k = 0; k < 4; ++k) {
                int i = iq*4 + k;
                #pragma unroll
                for (int c4 = 0; c4 < 4; ++c4) {
                    float4 add = make_float4(P[k][c4*4], P[k][c4*4+1], P[k][c4*4+2], P[k][c4*4+3]);
                    if (hh == 0) sO1[i*4 + c4] = add;
                    else {
                        float4 cur = sO1[i*4 + c4];
                        cur.x += add.x; cur.y += add.y; cur.z += add.z; cur.w += add.w;
                        sO1[i*4 + c4] = cur;
                    }
                }
            }
        }
        __syncthreads();
    }
    float* obase = O1g + ((size_t)b*Nn + i0)*16;
    for (int f = tx; f < TI*4; f += 256) ((float4*)obase)[f] = sO1[f];
}

// ---------------------------------------------------------------- K6: finalize bw/fw + modes + read vectors
template<int NT>
__global__ void k_read(const float* __restrict__ memnew, const float* __restrict__ O1g,
                       const float* __restrict__ partg, const float* __restrict__ cr,
                       const float* __restrict__ ww, const float* __restrict__ prec,
                       const float* __restrict__ c12, const float* __restrict__ rmodes,
                       float* __restrict__ out)
{
    __shared__ float s_o2[256][17];
    __shared__ float s_o1[256][17];
    __shared__ float s_rw[256][Rr];
    __shared__ float s_rm[Rr*3];
    __shared__ float s_c12[16];
    __shared__ float s_part[2][Ww][Rr];
    int b = blockIdx.x >> 3, slice = blockIdx.x & 7;
    int n0 = slice * 256;
    int tx = threadIdx.x;
    if (tx < Rr*3) s_rm[tx] = rmodes[b*Rr*3 + tx];
    if (tx < 16)   s_c12[tx] = c12[b*16 + tx];
    __syncthreads();
    // sum partials -> O2, load O1 (thread <-> f4)
    #pragma unroll
    for (int k = 0; k < 4; ++k) {
        int f = k*256 + tx;
        int n = f >> 2, c4 = f & 3;
        float4 acc = make_float4(0.f,0.f,0.f,0.f);
        for (int t = 0; t < NT; ++t) {
            float4 v = ((const float4*)(partg + ((size_t)(t*BS + b)*Nn + n0)*16))[f];
            acc.x += v.x; acc.y += v.y; acc.z += v.z; acc.w += v.w;
        }
        s_o2[n][c4*4+0] = acc.x; s_o2[n][c4*4+1] = acc.y;
        s_o2[n][c4*4+2] = acc.z; s_o2[n][c4*4+3] = acc.w;
        float4 o1 = ((const float4*)(O1g + ((size_t)b*Nn + n0)*16))[f];
        s_o1[n][c4*4+0] = o1.x; s_o1[n][c4*4+1] = o1.y;
        s_o1[n][c4*4+2] = o1.z; s_o1[n][c4*4+3] = o1.w;
    }
    __syncthreads();
    // rw[n][r] = bw*m0 + cr*m1 + fw*m2
    {
        int n = n0 + tx;
        float wwv = ww[b*Nn + n], pv = prec[b*Nn + n];
        float4 cr0 = *(const float4*)(cr + ((size_t)b*Nn + n)*Rr);
        float4 cr1 = *(const float4*)(cr + ((size_t)b*Nn + n)*Rr + 4);
        float crv[8] = {cr0.x,cr0.y,cr0.z,cr0.w,cr1.x,cr1.y,cr1.z,cr1.w};
        #pragma unroll
        for (int r = 0; r < 8; ++r) {
            float bwv = (1.f - wwv)*s_o1[tx][r] - s_o1[tx][8+r] + wwv*s_c12[r];
            float fwv = (1.f - wwv)*s_o2[tx][r] - s_o2[tx][8+r] + pv*s_c12[8+r];
            s_rw[tx][r] = bwv*s_rm[r*3+0] + crv[r]*s_rm[r*3+1] + fwv*s_rm[r*3+2];
        }
    }
    __syncthreads();
    // contraction: out[b][w][r] += sum_n memnew[n][w]*rw[n][r]
    int w = tx & 127, hh = tx >> 7;
    float acc[Rr] = {0,0,0,0,0,0,0,0};
    for (int nl = hh*128; nl < hh*128 + 128; ++nl) {
        float mval = memnew[(size_t)(n0 + nl)*Ww + w];
        #pragma unroll
        for (int r = 0; r < Rr; ++r) acc[r] += mval * s_rw[nl][r];
    }
    #pragma unroll
    for (int r = 0; r < Rr; ++r) s_part[hh][w][r] = acc[r];
    __syncthreads();
    if (hh == 0) {
        #pragma unroll
        for (int r = 0; r < Rr; ++r)
            unsafeAtomicAdd(&out[(w*Rr + r) + b*Ww*Rr], s_part[0][w][r] + s_part[1][w][r]);
    }
}

// ----------------------------------------------------------------
extern "C" void kernel_launch(void* const* d_in, const int* in_sizes, int n_in,
                              void* d_out, int out_size, void* d_ws, size_t ws_size,
                              hipStream_t stream) {
    const float* mem    = (const float*)d_in[0];
    const float* usage  = (const float*)d_in[1];
    const float* prec   = (const float*)d_in[2];
    const float* Lmat   = (const float*)d_in[3];
    const float* lrw    = (const float*)d_in[4];
    const float* rkeys  = (const float*)d_in[5];
    const float* rstr   = (const float*)d_in[6];
    const float* wkey   = (const float*)d_in[7];
    const float* wstr   = (const float*)d_in[8];
    const float* erasev = (const float*)d_in[9];
    const float* wvec   = (const float*)d_in[10];
    const float* agate  = (const float*)d_in[12];
    const float* wgate  = (const float*)d_in[13];
    const float* rmodes = (const float*)d_in[14];

    float* ws       = (float*)d_ws;
    float* alloc_   = ws + OFF_ALLOC;
    float* ww_      = ws + OFF_WW;
    float* memnew_  = ws + OFF_MEMNEW;
    float* memnorm_ = ws + OFF_MEMNORM;
    float* cr_      = ws + OFF_CR;
    float* M2_      = ws + OFF_M2;
    float* O1_      = ws + OFF_O1;
    float* c12_     = ws + OFF_C12;
    float* part_    = ws + OFF_PART;
    float* outf     = (float*)d_out;

    hipMemsetAsync(outf, 0, (size_t)out_size*sizeof(float), stream);

    k_alloc <<<BS,    256, 0, stream>>>(usage, alloc_);
    k_ww    <<<BS,    256, 0, stream>>>(mem, wkey, wstr, agate, wgate, alloc_, ww_);
    k_memnew<<<Nn/2,  256, 0, stream>>>(mem, ww_, erasev, wvec, memnew_, memnorm_);
    k_cr    <<<BS*Rr, 256, 0, stream>>>(memnew_, memnorm_, rkeys, rstr, cr_);
    k_prep  <<<BS,    256, 0, stream>>>(lrw, ww_, prec, M2_, c12_);

    const bool big = ws_size >= (size_t)(OFF_PART + (size_t)16*BS*Nn*16) * 4;
    if (big) {
        k_link<128,16><<<BS*16, 256, 0, stream>>>(Lmat, M2_, O1_, part_);
        k_read<16>    <<<BS*8,  256, 0, stream>>>(memnew_, O1_, part_, cr_, ww_, prec, c12_, rmodes, outf);
    } else {
        k_link<256,8> <<<BS*8,  256, 0, stream>>>(Lmat, M2_, O1_, part_);
        k_read<8>     <<<BS*8,  256, 0, stream>>>(memnew_, O1_, part_, cr_, ww_, prec, c12_, rmodes, outf);
    }
}